// Round 15
// baseline (1388.503 us; speedup 1.0000x reference)
//
#include <hip/hip_runtime.h>
#include <hip/hip_bf16.h>
#include <stdint.h>

#define TT 1024
#define BBATCH 256
#define DD 256
#define HH 256
#define G4 1024   // 4*H
#define BG (BBATCH * G4)

typedef float f32x4 __attribute__((ext_vector_type(4)));
typedef short bf16x8 __attribute__((ext_vector_type(8)));
typedef int   i32x4  __attribute__((ext_vector_type(4)));
typedef unsigned long long u64;

__device__ __forceinline__ float bf2f(unsigned int u) {
  union { unsigned int i; float f; } v; v.i = u << 16; return v.f;
}
__device__ __forceinline__ unsigned short f2bf(float f) {
  union { float f; unsigned int i; } v; v.f = f;
  unsigned int r = v.i + 0x7FFFu + ((v.i >> 16) & 1u);
  return (unsigned short)(r >> 16);
}

// ---------------- prep kernels ----------------

// W_ih fp32 [1024 g][256 k] -> bf16 frag-packed (consumed straight from global):
// elem = (nt8*4+ks)*8192 + (((wc*4+sec)*2+kk)*64 + lane)*8 + el   (nc = nt8*2+wc = n>>4)
__global__ void prep_wih(const float* __restrict__ wih, unsigned short* __restrict__ out) {
  int g = blockIdx.x;          // 0..1023
  int lane = threadIdx.x;      // 0..63
  int sec = g >> 8, n = g & 255;
  int nt8 = n >> 5, wc = (n >> 4) & 1, lr = n & 15;
  int k0 = lane * 4;
  int ks = k0 >> 6, kk = (k0 >> 5) & 1, hi = (k0 >> 3) & 3, j = k0 & 7;
  size_t us = (size_t)(nt8 * 4 + ks) * 8192
            + (size_t)((((wc * 4 + sec) * 2 + kk) * 64) + (lr | (hi << 4))) * 8 + j;
#pragma unroll
  for (int j2 = 0; j2 < 4; ++j2) out[us + j2] = f2bf(wih[g * 256 + k0 + j2]);
}

// W_y fp32 [256 k][256 d] -> bf16 frag-packed for y_gemm B:
// elem = ((dc*8 + k0)*64 + (lr|hi<<4))*8 + el, dc=d>>4, lr=d&15, k0=k>>5, hi=(k>>3)&3, el=k&7
__global__ void prep_wyt(const float* __restrict__ wy, unsigned short* __restrict__ wyt) {
  int k = blockIdx.x;   // 0..255
  int d = threadIdx.x;  // 0..255
  int dc = d >> 4, lr = d & 15;
  int k0 = k >> 5, hi = (k >> 3) & 3, el = k & 7;
  wyt[((size_t)(dc * 8 + k0) * 64 + (lr | (hi << 4))) * 8 + el] = f2bf(wy[k * 256 + d]);
}

// W_hh fp32 [1024 g][256 k] -> per-row-scaled int8 packed in MFMA B-frag order for the
// 16-wave scan: g = sec*256 + n, n = w*16 + cl. Frag slot [((w*4+sec)*4+kt)*64 + lane].
__global__ void prep_whh(const float* __restrict__ whh, const float* __restrict__ h0,
                         signed char* __restrict__ wq, float* __restrict__ dsc,
                         float* __restrict__ hh0) {
  int g = blockIdx.x;
  int lane = threadIdx.x;
  float v[4];
  float mx = 0.f, acc = 0.f;
#pragma unroll
  for (int j = 0; j < 4; ++j) {
    v[j] = whh[g * 256 + lane * 4 + j];
    mx = fmaxf(mx, fabsf(v[j]));
    acc += v[j] * h0[lane * 4 + j];
  }
#pragma unroll
  for (int off = 32; off; off >>= 1) {
    mx  = fmaxf(mx, __shfl_xor(mx, off));
    acc = acc + __shfl_xor(acc, off);
  }
  mx = fmaxf(mx, 1e-12f);
  if (lane == 0) { dsc[g] = mx / (127.f * 127.f); hh0[g] = acc; }
  int sec = g >> 8, w = (g >> 4) & 15, cl = g & 15;
  float inv = 127.f / mx;
  int k0 = lane * 4;
  int kt = k0 >> 6, hi = (k0 >> 4) & 3, jj = k0 & 15;
  int base = (((w * 4 + sec) * 4 + kt) * 64 + (cl | (hi << 4))) * 16 + jj;
#pragma unroll
  for (int j = 0; j < 4; ++j) {
    int q = (int)rintf(v[j] * inv);
    q = q > 127 ? 127 : (q < -127 ? -127 : q);
    wq[base + j] = (signed char)q;
  }
}

// ---------------- phase 1: xw = x @ W_ih^T + b_ih (gate-packed bf16) ----
// grid 4096, block 256 (4 waves), 3 blocks/CU. One block = 64 trows x ALL 1024 g:
// A-tile (64x256 bf16, 32KB LDS) staged ONCE; waves split N 4-ways per nt4 iteration
// (wave wv owns n-chunk nt4*4+wv); B-frags straight from frag-packed global wb.
// NO barriers in the main loop.
__global__ __launch_bounds__(256, 3) void xw_gemm(const float* __restrict__ x,
                                                  const unsigned short* __restrict__ wb,
                                                  const float* __restrict__ bih,
                                                  const float* __restrict__ hh0,
                                                  unsigned short* __restrict__ xw) {
  __shared__ __align__(16) char lds[32768];   // A: 64 rows x 512B, XOR-swizzled
  int tid = threadIdx.x;
  int mt = blockIdx.x;          // 0..4095
  int bb = mt >> 4;
  int t0 = (mt & 15) * 64;
  int lane = tid & 63, wv = tid >> 6;
  int lr = lane & 15, hi = lane >> 4;

  const float* xbase = x + ((size_t)bb * TT + t0) * DD;

  // stage A-tile: 64 rows x 256 fp32 = 4096 float4 -> 32KB bf16
#pragma unroll 4
  for (int i = 0; i < 16; ++i) {
    int idx = i * 256 + tid;            // float4 index, 0..4095
    int row = idx >> 6, c4 = idx & 63;
    float4 v = *(const float4*)(xbase + (size_t)idx * 4);
    u64 pk = (u64)f2bf(v.x) | ((u64)f2bf(v.y) << 16)
           | ((u64)f2bf(v.z) << 32) | ((u64)f2bf(v.w) << 48);
    *(u64*)(lds + row * 512 + ((c4 * 8) ^ ((row & 7) << 4))) = pk;
  }
  __syncthreads();

#pragma unroll 1
  for (int nt4 = 0; nt4 < 4; ++nt4) {
    int nc = nt4 * 4 + wv;              // n-chunk of 16, 0..15
    const unsigned short* wbase = wb + (size_t)(nc >> 1) * 4 * 8192;
    int wc2 = nc & 1;
    f32x4 acc[4][4];   // [m][sec]
#pragma unroll
    for (int m = 0; m < 4; ++m)
#pragma unroll
      for (int s = 0; s < 4; ++s) acc[m][s] = (f32x4){0.f, 0.f, 0.f, 0.f};
#pragma unroll
    for (int ks = 0; ks < 4; ++ks) {
#pragma unroll
      for (int kk = 0; kk < 2; ++kk) {
        bf16x8 a[4], b[4];
#pragma unroll
        for (int m = 0; m < 4; ++m) {
          int row = m * 16 + lr;
          a[m] = *(const bf16x8*)(lds + row * 512
                                  + (((ks * 2 + kk) * 64 + hi * 16) ^ ((row & 7) << 4)));
        }
#pragma unroll
        for (int s = 0; s < 4; ++s)
          b[s] = *(const bf16x8*)(wbase + (size_t)ks * 8192
                                  + (size_t)(((wc2 * 4 + s) * 2 + kk) * 64 + lane) * 8);
#pragma unroll
        for (int m = 0; m < 4; ++m)
#pragma unroll
          for (int s = 0; s < 4; ++s)
            acc[m][s] = __builtin_amdgcn_mfma_f32_16x16x32_bf16(a[m], b[s], acc[m][s], 0, 0, 0);
      }
    }
    // epilogue: pack 4 secs -> u64, add bias (+hh0 at t==0), contiguous 8B stores
    int n = nc * 16 + lr;
    float bias[4], h0a[4];
#pragma unroll
    for (int s = 0; s < 4; ++s) { bias[s] = bih[s * 256 + n]; h0a[s] = hh0[s * 256 + n]; }
#pragma unroll
    for (int m = 0; m < 4; ++m) {
#pragma unroll
      for (int r = 0; r < 4; ++r) {
        int trow = t0 + m * 16 + hi * 4 + r;
        float e[4];
#pragma unroll
        for (int s = 0; s < 4; ++s)
          e[s] = acc[m][s][r] + bias[s] + (trow == 0 ? h0a[s] : 0.f);
        u64 pk = (u64)f2bf(e[0]) | ((u64)f2bf(e[1]) << 16)
               | ((u64)f2bf(e[2]) << 32) | ((u64)f2bf(e[3]) << 48);
        *(u64*)(xw + ((size_t)trow * BBATCH + bb) * G4 + (size_t)n * 4) = pk;
      }
    }
  }
}

// ---------------- phase 2: the scan ----------------
// 64 blocks x 1024 threads (16 waves, 4/SIMD). hs(t) written lane-contiguous (one full
// 128B line per wave) into the block's OWN batch slice of row t (consumed this step):
// elem = t*BG + b0*G4 + tid. No cross-block footprint -> no dispatch-order dependence.
__global__ __launch_bounds__(1024, 1) void lstm_scan(unsigned short* xw,
                                                     const signed char* __restrict__ wq,
                                                     const float* __restrict__ dsc,
                                                     const float* __restrict__ c0,
                                                     float* __restrict__ out) {
  __shared__ __align__(16) signed char hq[2][4][64][16];  // 8KB, double-buffered int8 h A-frags
  int tid = threadIdx.x;
  int lane = tid & 63, wv = tid >> 6;
  int lr = lane & 15, q = lane >> 4;
  int b0 = blockIdx.x * 4;
  signed char* hqb = (signed char*)hq;
  int nn = wv * 16 + lr;

  // resident W_hh int8 B-frags: 16 i32x4 = 64 VGPRs
  i32x4 wf[4][4];
  {
    const i32x4* wp = (const i32x4*)wq;
#pragma unroll
    for (int sec = 0; sec < 4; ++sec)
#pragma unroll
      for (int kt = 0; kt < 4; ++kt) wf[sec][kt] = wp[((wv * 4 + sec) * 4 + kt) * 64 + lane];
  }
  float dr[4];
#pragma unroll
  for (int sec = 0; sec < 4; ++sec) dr[sec] = dsc[sec * 256 + nn];
  float cr = c0[nn], lh = 0.f;

  // zero both hq buffers (8KB = 1024 threads * 8B)
  *(u64*)(hqb + tid * 8) = 0ull;

  // per-lane pointers
  unsigned short* ldb = xw + (size_t)(b0 + q) * G4 + (size_t)nn * 4;
  unsigned short* hsp = xw + (size_t)b0 * G4 + tid;   // hs store base (block-own slice, row += t)
  u64 xq[4];
#pragma unroll
  for (int s = 0; s < 2; ++s) {
    xq[s] = *(const u64*)ldb;
    ldb += (size_t)BG;
  }

  const int hqr = lane * 16;
  // producer write: kt = wv>>2, hi = wv&3, row = 4q, byte j = lr
  const int hqw = (wv >> 2) * 1024 + (wv & 3) * 256 + q * 64 + lr;
  const i32x4 zero4 = {0, 0, 0, 0};

  __syncthreads();  // hq zero visible

#define STEP(XC, XL, RB) { \
    XL = *(const u64*)ldb; \
    ldb += (size_t)BG; \
    i32x4 acc[4]; \
    __builtin_amdgcn_s_setprio(1); \
    _Pragma("unroll") \
    for (int kt = 0; kt < 4; ++kt) { \
      i32x4 af = *(const i32x4*)(hqb + (RB) + hqr + kt * 1024); \
      _Pragma("unroll") \
      for (int sec = 0; sec < 4; ++sec) \
        acc[sec] = __builtin_amdgcn_mfma_i32_16x16x64_i8(af, wf[sec][kt], kt == 0 ? zero4 : acc[sec], 0, 0, 0); \
    } \
    __builtin_amdgcn_s_setprio(0); \
    { \
      u64 v = XC; \
      float gi = fmaf(dr[0], (float)acc[0][0], bf2f((unsigned int)(v & 0xffffu))); \
      float gf = fmaf(dr[1], (float)acc[1][0], bf2f((unsigned int)((v >> 16) & 0xffffu))); \
      float gj = fmaf(dr[2], (float)acc[2][0], bf2f((unsigned int)((v >> 32) & 0xffffu))); \
      float go = fmaf(dr[3], (float)acc[3][0], bf2f((unsigned int)(v >> 48))); \
      float iv = __builtin_amdgcn_rcpf(1.f + __expf(-gi)); \
      float fv = __builtin_amdgcn_rcpf(1.f + __expf(-gf)); \
      float ov = __builtin_amdgcn_rcpf(1.f + __expf(-go)); \
      float jv = fmaf(-2.f, __builtin_amdgcn_rcpf(1.f + __expf(2.f * gj)), 1.f); \
      float cn = fmaf(fv, cr, iv * jv); \
      cr = cn; \
      float th = fmaf(-2.f, __builtin_amdgcn_rcpf(1.f + __expf(2.f * cn)), 1.f); \
      float hn = ov * th; \
      lh = hn; \
      hqb[((RB) ^ 4096) + hqw] = (signed char)(int)rintf(hn * 127.f); \
      hsp[0] = f2bf(hn); \
    } \
    hsp += (size_t)BG; \
    asm volatile("s_waitcnt lgkmcnt(0)" ::: "memory"); \
    __builtin_amdgcn_s_barrier(); \
  }

#pragma unroll 1
  for (int t = 0; t < TT; t += 4) {
    STEP(xq[0], xq[2], 0)
    STEP(xq[1], xq[3], 4096)
    STEP(xq[2], xq[0], 0)
    STEP(xq[3], xq[1], 4096)
  }
#undef STEP

  const size_t youts = (size_t)BBATCH * TT * DD;
  out[youts + (size_t)(b0 + q) * HH + nn] = lh;
  out[youts + (size_t)BBATCH * HH + (size_t)(b0 + q) * HH + nn] = cr;
}

// ---------------- phase 3: y = hs @ W_y + b_y ----------------
// hs element (t,b,n) at elem t*BG + (b>>2)*4096 + (n>>4)*64 + (b&3)*16 + (n&15).
// wyt frag-packed: B-loads are wave-contiguous 1KB streams.
__global__ __launch_bounds__(256, 4) void y_gemm(const unsigned short* __restrict__ hsx,
                                                 const unsigned short* __restrict__ wyt,
                                                 const float* __restrict__ by,
                                                 float* __restrict__ y) {
  __shared__ __align__(16) unsigned short ha[64 * 256];  // 32KB
  int tid = threadIdx.x;
  int mt = blockIdx.x;
  int bb = mt >> 4;
  int t0 = (mt & 15) * 64;
  {
    int row = tid >> 2, qt = tid & 3;
    int t = t0 + row;
    const unsigned short* src = hsx + (size_t)t * BG + (size_t)(bb >> 2) * 4096 + (bb & 3) * 16;
#pragma unroll
    for (int i = 0; i < 8; ++i) {
      int u = qt + i * 4;   // 16B unit, 0..31
      int4 vv = *(const int4*)(src + (u >> 1) * 64 + (u & 1) * 8);
      *(int4*)((char*)ha + row * 512 + ((u * 16) ^ ((row & 7) << 4))) = vv;
    }
  }
  __syncthreads();
  int lane = tid & 63, wv = tid >> 6;
  int wr = wv >> 1, wc = wv & 1;
  int lr = lane & 15, hi = lane >> 4;
#pragma unroll 1
  for (int dblk = 0; dblk < 2; ++dblk) {
    f32x4 acc[2][4];
#pragma unroll
    for (int a = 0; a < 2; ++a)
#pragma unroll
      for (int b = 0; b < 4; ++b) acc[a][b] = (f32x4){0.f, 0.f, 0.f, 0.f};
#pragma unroll
    for (int k0 = 0; k0 < 8; ++k0) {
      bf16x8 a[2], b[4];
#pragma unroll
      for (int mti = 0; mti < 2; ++mti) {
        int row = wr * 32 + mti * 16 + lr;
        a[mti] = *(const bf16x8*)((const char*)ha + row * 512 + ((k0 * 64 + hi * 16) ^ ((row & 7) << 4)));
      }
#pragma unroll
      for (int nt = 0; nt < 4; ++nt) {
        int dc = dblk * 8 + wc * 4 + nt;
        b[nt] = *(const bf16x8*)(wyt + ((size_t)(dc * 8 + k0) * 64 + lane) * 8);
#pragma unroll
        for (int mti = 0; mti < 2; ++mti)
          acc[mti][nt] = __builtin_amdgcn_mfma_f32_16x16x32_bf16(a[mti], b[nt], acc[mti][nt], 0, 0, 0);
      }
    }
#pragma unroll
    for (int mti = 0; mti < 2; ++mti)
#pragma unroll
      for (int nt = 0; nt < 4; ++nt) {
        int d = (dblk * 8 + wc * 4 + nt) * 16 + lr;
        float bv = by[d];
#pragma unroll
        for (int r = 0; r < 4; ++r) {
          int trow = t0 + wr * 32 + mti * 16 + hi * 4 + r;
          y[((size_t)bb * TT + trow) * DD + d] = acc[mti][nt][r] + bv;
        }
      }
  }
}

// ---------------- launch ----------------
extern "C" void kernel_launch(void* const* d_in, const int* in_sizes, int n_in,
                              void* d_out, int out_size, void* d_ws, size_t ws_size,
                              hipStream_t stream) {
  const float* x   = (const float*)d_in[0];
  const float* wih = (const float*)d_in[1];
  const float* bih = (const float*)d_in[2];
  const float* whh = (const float*)d_in[3];
  const float* h0  = (const float*)d_in[4];
  const float* c0  = (const float*)d_in[5];
  const float* wy  = (const float*)d_in[6];
  const float* by  = (const float*)d_in[7];
  float* out = (float*)d_out;
  char* ws = (char*)d_ws;

  size_t off = 0;
  unsigned short* xw = (unsigned short*)(ws + off);
  off += (size_t)(TT + 2) * BG * 2;   // 512MB + 2-row prefetch slack
  unsigned short* wbf = (unsigned short*)(ws + off); off += (size_t)G4 * DD * 2;
  unsigned short* wyt = (unsigned short*)(ws + off); off += (size_t)HH * DD * 2;
  signed char* wq = (signed char*)(ws + off); off += (size_t)G4 * HH;
  float* dsc = (float*)(ws + off); off += G4 * 4;
  float* hh0 = (float*)(ws + off); off += G4 * 4;

  hipLaunchKernelGGL(prep_wih, dim3(1024), dim3(64), 0, stream, wih, wbf);
  hipLaunchKernelGGL(prep_wyt, dim3(256), dim3(256), 0, stream, wy, wyt);
  hipLaunchKernelGGL(prep_whh, dim3(1024), dim3(64), 0, stream, whh, h0, wq, dsc, hh0);
  hipLaunchKernelGGL(xw_gemm, dim3(4096), dim3(256), 0, stream, x, wbf, bih, hh0, xw);
  hipLaunchKernelGGL(lstm_scan, dim3(64), dim3(1024), 0, stream, xw, wq, dsc, c0, out);
  hipLaunchKernelGGL(y_gemm, dim3(4096), dim3(256), 0, stream, xw, wyt, by, out);
}

// Round 16
// 1109.971 us; speedup vs baseline: 1.2509x; 1.2509x over previous
//
#include <hip/hip_runtime.h>
#include <hip/hip_bf16.h>
#include <stdint.h>

#define TT 1024
#define BBATCH 256
#define DD 256
#define HH 256
#define G4 1024   // 4*H
#define BG (BBATCH * G4)

typedef float f32x4 __attribute__((ext_vector_type(4)));
typedef short bf16x8 __attribute__((ext_vector_type(8)));
typedef int   i32x4  __attribute__((ext_vector_type(4)));
typedef unsigned long long u64;

__device__ __forceinline__ float bf2f(unsigned int u) {
  union { unsigned int i; float f; } v; v.i = u << 16; return v.f;
}
__device__ __forceinline__ unsigned short f2bf(float f) {
  union { float f; unsigned int i; } v; v.f = f;
  unsigned int r = v.i + 0x7FFFu + ((v.i >> 16) & 1u);
  return (unsigned short)(r >> 16);
}

// ---------------- prep kernels ----------------

// W_ih fp32 [1024 g][256 k] -> bf16 frag-packed (consumed straight from global):
// elem = (nt8*4+ks)*8192 + (((wc*4+sec)*2+kk)*64 + lane)*8 + el
__global__ void prep_wih(const float* __restrict__ wih, unsigned short* __restrict__ out) {
  int g = blockIdx.x;          // 0..1023
  int lane = threadIdx.x;      // 0..63
  int sec = g >> 8, n = g & 255;
  int nt8 = n >> 5, wc = (n >> 4) & 1, lr = n & 15;
  int k0 = lane * 4;
  int ks = k0 >> 6, kk = (k0 >> 5) & 1, hi = (k0 >> 3) & 3, j = k0 & 7;
  size_t us = (size_t)(nt8 * 4 + ks) * 8192
            + (size_t)((((wc * 4 + sec) * 2 + kk) * 64) + (lr | (hi << 4))) * 8 + j;
#pragma unroll
  for (int j2 = 0; j2 < 4; ++j2) out[us + j2] = f2bf(wih[g * 256 + k0 + j2]);
}

// W_y fp32 [256 k][256 d] -> bf16 frag-packed for y_gemm B:
// elem = ((dc*8 + k0)*64 + (lr|hi<<4))*8 + el, dc=d>>4, lr=d&15, k0=k>>5, hi=(k>>3)&3, el=k&7
__global__ void prep_wyt(const float* __restrict__ wy, unsigned short* __restrict__ wyt) {
  int k = blockIdx.x;   // 0..255
  int d = threadIdx.x;  // 0..255
  int dc = d >> 4, lr = d & 15;
  int k0 = k >> 5, hi = (k >> 3) & 3, el = k & 7;
  wyt[((size_t)(dc * 8 + k0) * 64 + (lr | (hi << 4))) * 8 + el] = f2bf(wy[k * 256 + d]);
}

// W_hh fp32 [1024 g][256 k] -> per-row-scaled int8 packed in MFMA B-frag order for the
// 16-wave scan: g = sec*256 + n, n = w*16 + cl. Frag slot [((w*4+sec)*4+kt)*64 + lane].
__global__ void prep_whh(const float* __restrict__ whh, const float* __restrict__ h0,
                         signed char* __restrict__ wq, float* __restrict__ dsc,
                         float* __restrict__ hh0) {
  int g = blockIdx.x;
  int lane = threadIdx.x;
  float v[4];
  float mx = 0.f, acc = 0.f;
#pragma unroll
  for (int j = 0; j < 4; ++j) {
    v[j] = whh[g * 256 + lane * 4 + j];
    mx = fmaxf(mx, fabsf(v[j]));
    acc += v[j] * h0[lane * 4 + j];
  }
#pragma unroll
  for (int off = 32; off; off >>= 1) {
    mx  = fmaxf(mx, __shfl_xor(mx, off));
    acc = acc + __shfl_xor(acc, off);
  }
  mx = fmaxf(mx, 1e-12f);
  if (lane == 0) { dsc[g] = mx / (127.f * 127.f); hh0[g] = acc; }
  int sec = g >> 8, w = (g >> 4) & 15, cl = g & 15;
  float inv = 127.f / mx;
  int k0 = lane * 4;
  int kt = k0 >> 6, hi = (k0 >> 4) & 3, jj = k0 & 15;
  int base = (((w * 4 + sec) * 4 + kt) * 64 + (cl | (hi << 4))) * 16 + jj;
#pragma unroll
  for (int j = 0; j < 4; ++j) {
    int q = (int)rintf(v[j] * inv);
    q = q > 127 ? 127 : (q < -127 ? -127 : q);
    wq[base + j] = (signed char)q;
  }
}

// ---------------- phase 1: xw = x @ W_ih^T + b_ih (gate-packed bf16) ----
// grid 2048, block 256 (4 waves), 2 blocks/CU. One block = 128 trows x ALL 1024 g:
// A-tile (128x256 bf16, 64KB LDS) staged ONCE (8192 float4 = 32 iters x 256 thr);
// 8 nt8 slices consume B-frags straight from frag-packed global wb (wave-contiguous
// 1KB loads, 512KB L2-resident). NO barriers in the main loop.  [R14-validated]
__global__ __launch_bounds__(256, 2) void xw_gemm(const float* __restrict__ x,
                                                  const unsigned short* __restrict__ wb,
                                                  const float* __restrict__ bih,
                                                  const float* __restrict__ hh0,
                                                  unsigned short* __restrict__ xw) {
  __shared__ __align__(16) char lds[65536];   // A: 128 rows x 512B, XOR-swizzled
  int tid = threadIdx.x;
  int mt = blockIdx.x;          // 0..2047
  int bb = mt >> 3;
  int t0 = (mt & 7) * 128;
  int lane = tid & 63, wv = tid >> 6;
  int wr = wv >> 1, wc = wv & 1;
  int lr = lane & 15, hi = lane >> 4;

  const float* xbase = x + ((size_t)bb * TT + t0) * DD;

  // stage full A-tile: 128 rows x 256 fp32 = 8192 float4 -> 64KB bf16
#pragma unroll 8
  for (int i = 0; i < 32; ++i) {
    int idx = i * 256 + tid;            // float4 index over the tile, 0..8191
    int row = idx >> 6, c4 = idx & 63;
    float4 v = *(const float4*)(xbase + (size_t)idx * 4);
    u64 pk = (u64)f2bf(v.x) | ((u64)f2bf(v.y) << 16)
           | ((u64)f2bf(v.z) << 32) | ((u64)f2bf(v.w) << 48);
    *(u64*)(lds + row * 512 + ((c4 * 8) ^ ((row & 7) << 4))) = pk;
  }
  __syncthreads();

#pragma unroll 1
  for (int nt8 = 0; nt8 < 8; ++nt8) {
    const unsigned short* wbase = wb + (size_t)nt8 * 4 * 8192;
    f32x4 acc[4][4];   // [mti][sec]
#pragma unroll
    for (int m = 0; m < 4; ++m)
#pragma unroll
      for (int s = 0; s < 4; ++s) acc[m][s] = (f32x4){0.f, 0.f, 0.f, 0.f};
#pragma unroll
    for (int ks = 0; ks < 4; ++ks) {
#pragma unroll
      for (int kk = 0; kk < 2; ++kk) {
        bf16x8 a[4], b[4];
#pragma unroll
        for (int m = 0; m < 4; ++m) {
          int row = wr * 64 + m * 16 + lr;
          a[m] = *(const bf16x8*)(lds + row * 512
                                  + (((ks * 2 + kk) * 64 + hi * 16) ^ ((row & 7) << 4)));
        }
#pragma unroll
        for (int s = 0; s < 4; ++s)
          b[s] = *(const bf16x8*)(wbase + (size_t)ks * 8192
                                  + (size_t)(((wc * 4 + s) * 2 + kk) * 64 + lane) * 8);
#pragma unroll
        for (int m = 0; m < 4; ++m)
#pragma unroll
          for (int s = 0; s < 4; ++s)
            acc[m][s] = __builtin_amdgcn_mfma_f32_16x16x32_bf16(a[m], b[s], acc[m][s], 0, 0, 0);
      }
    }
    // epilogue: pack 4 secs -> u64, add bias (+hh0 at t==0), contiguous 8B stores
    int n = nt8 * 32 + wc * 16 + lr;
    float bias[4], h0a[4];
#pragma unroll
    for (int s = 0; s < 4; ++s) { bias[s] = bih[s * 256 + n]; h0a[s] = hh0[s * 256 + n]; }
#pragma unroll
    for (int m = 0; m < 4; ++m) {
#pragma unroll
      for (int r = 0; r < 4; ++r) {
        int trow = t0 + wr * 64 + m * 16 + hi * 4 + r;
        float e[4];
#pragma unroll
        for (int s = 0; s < 4; ++s)
          e[s] = acc[m][s][r] + bias[s] + (trow == 0 ? h0a[s] : 0.f);
        u64 pk = (u64)f2bf(e[0]) | ((u64)f2bf(e[1]) << 16)
               | ((u64)f2bf(e[2]) << 32) | ((u64)f2bf(e[3]) << 48);
        *(u64*)(xw + ((size_t)trow * BBATCH + bb) * G4 + (size_t)n * 4) = pk;
      }
    }
  }
}

// ---------------- phase 2: the scan ----------------
// 64 blocks x 1024 threads (16 waves, 4/SIMD). hs(t) written lane-contiguous (one full
// 128B line per wave) into the block's OWN batch slice of row t (consumed this step):
// elem = t*BG + b0*G4 + tid. No cross-block footprint -> no dispatch-order dependence.
__global__ __launch_bounds__(1024, 1) void lstm_scan(unsigned short* xw,
                                                     const signed char* __restrict__ wq,
                                                     const float* __restrict__ dsc,
                                                     const float* __restrict__ c0,
                                                     float* __restrict__ out) {
  __shared__ __align__(16) signed char hq[2][4][64][16];  // 8KB, double-buffered int8 h A-frags
  int tid = threadIdx.x;
  int lane = tid & 63, wv = tid >> 6;
  int lr = lane & 15, q = lane >> 4;
  int b0 = blockIdx.x * 4;
  signed char* hqb = (signed char*)hq;
  int nn = wv * 16 + lr;

  // resident W_hh int8 B-frags: 16 i32x4 = 64 VGPRs
  i32x4 wf[4][4];
  {
    const i32x4* wp = (const i32x4*)wq;
#pragma unroll
    for (int sec = 0; sec < 4; ++sec)
#pragma unroll
      for (int kt = 0; kt < 4; ++kt) wf[sec][kt] = wp[((wv * 4 + sec) * 4 + kt) * 64 + lane];
  }
  float dr[4];
#pragma unroll
  for (int sec = 0; sec < 4; ++sec) dr[sec] = dsc[sec * 256 + nn];
  float cr = c0[nn], lh = 0.f;

  // zero both hq buffers (8KB = 1024 threads * 8B)
  *(u64*)(hqb + tid * 8) = 0ull;

  // per-lane pointers
  unsigned short* ldb = xw + (size_t)(b0 + q) * G4 + (size_t)nn * 4;
  unsigned short* hsp = xw + (size_t)b0 * G4 + tid;   // hs store base (block-own slice, row += t)
  u64 xq[4];
#pragma unroll
  for (int s = 0; s < 2; ++s) {
    xq[s] = *(const u64*)ldb;
    ldb += (size_t)BG;
  }

  const int hqr = lane * 16;
  // producer write: kt = wv>>2, hi = wv&3, row = 4q, byte j = lr
  const int hqw = (wv >> 2) * 1024 + (wv & 3) * 256 + q * 64 + lr;
  const i32x4 zero4 = {0, 0, 0, 0};

  __syncthreads();  // hq zero visible

#define STEP(XC, XL, RB) { \
    XL = *(const u64*)ldb; \
    ldb += (size_t)BG; \
    i32x4 acc[4]; \
    __builtin_amdgcn_s_setprio(1); \
    _Pragma("unroll") \
    for (int kt = 0; kt < 4; ++kt) { \
      i32x4 af = *(const i32x4*)(hqb + (RB) + hqr + kt * 1024); \
      _Pragma("unroll") \
      for (int sec = 0; sec < 4; ++sec) \
        acc[sec] = __builtin_amdgcn_mfma_i32_16x16x64_i8(af, wf[sec][kt], kt == 0 ? zero4 : acc[sec], 0, 0, 0); \
    } \
    __builtin_amdgcn_s_setprio(0); \
    { \
      u64 v = XC; \
      float gi = fmaf(dr[0], (float)acc[0][0], bf2f((unsigned int)(v & 0xffffu))); \
      float gf = fmaf(dr[1], (float)acc[1][0], bf2f((unsigned int)((v >> 16) & 0xffffu))); \
      float gj = fmaf(dr[2], (float)acc[2][0], bf2f((unsigned int)((v >> 32) & 0xffffu))); \
      float go = fmaf(dr[3], (float)acc[3][0], bf2f((unsigned int)(v >> 48))); \
      float iv = __builtin_amdgcn_rcpf(1.f + __expf(-gi)); \
      float fv = __builtin_amdgcn_rcpf(1.f + __expf(-gf)); \
      float ov = __builtin_amdgcn_rcpf(1.f + __expf(-go)); \
      float jv = fmaf(-2.f, __builtin_amdgcn_rcpf(1.f + __expf(2.f * gj)), 1.f); \
      float cn = fmaf(fv, cr, iv * jv); \
      cr = cn; \
      float th = fmaf(-2.f, __builtin_amdgcn_rcpf(1.f + __expf(2.f * cn)), 1.f); \
      float hn = ov * th; \
      lh = hn; \
      hqb[((RB) ^ 4096) + hqw] = (signed char)(int)rintf(hn * 127.f); \
      hsp[0] = f2bf(hn); \
    } \
    hsp += (size_t)BG; \
    asm volatile("s_waitcnt lgkmcnt(0)" ::: "memory"); \
    __builtin_amdgcn_s_barrier(); \
  }

#pragma unroll 1
  for (int t = 0; t < TT; t += 4) {
    STEP(xq[0], xq[2], 0)
    STEP(xq[1], xq[3], 4096)
    STEP(xq[2], xq[0], 0)
    STEP(xq[3], xq[1], 4096)
  }
#undef STEP

  const size_t youts = (size_t)BBATCH * TT * DD;
  out[youts + (size_t)(b0 + q) * HH + nn] = lh;
  out[youts + (size_t)BBATCH * HH + (size_t)(b0 + q) * HH + nn] = cr;
}

// ---------------- phase 3: y = hs @ W_y + b_y ----------------
// hs element (t,b,n) at elem t*BG + (b>>2)*4096 + (n>>4)*64 + (b&3)*16 + (n&15).
// wyt frag-packed: B-loads are wave-contiguous 1KB streams.
__global__ __launch_bounds__(256, 4) void y_gemm(const unsigned short* __restrict__ hsx,
                                                 const unsigned short* __restrict__ wyt,
                                                 const float* __restrict__ by,
                                                 float* __restrict__ y) {
  __shared__ __align__(16) unsigned short ha[64 * 256];  // 32KB
  int tid = threadIdx.x;
  int mt = blockIdx.x;
  int bb = mt >> 4;
  int t0 = (mt & 15) * 64;
  {
    int row = tid >> 2, qt = tid & 3;
    int t = t0 + row;
    const unsigned short* src = hsx + (size_t)t * BG + (size_t)(bb >> 2) * 4096 + (bb & 3) * 16;
#pragma unroll
    for (int i = 0; i < 8; ++i) {
      int u = qt + i * 4;   // 16B unit, 0..31
      int4 vv = *(const int4*)(src + (u >> 1) * 64 + (u & 1) * 8);
      *(int4*)((char*)ha + row * 512 + ((u * 16) ^ ((row & 7) << 4))) = vv;
    }
  }
  __syncthreads();
  int lane = tid & 63, wv = tid >> 6;
  int wr = wv >> 1, wc = wv & 1;
  int lr = lane & 15, hi = lane >> 4;
#pragma unroll 1
  for (int dblk = 0; dblk < 2; ++dblk) {
    f32x4 acc[2][4];
#pragma unroll
    for (int a = 0; a < 2; ++a)
#pragma unroll
      for (int b = 0; b < 4; ++b) acc[a][b] = (f32x4){0.f, 0.f, 0.f, 0.f};
#pragma unroll
    for (int k0 = 0; k0 < 8; ++k0) {
      bf16x8 a[2], b[4];
#pragma unroll
      for (int mti = 0; mti < 2; ++mti) {
        int row = wr * 32 + mti * 16 + lr;
        a[mti] = *(const bf16x8*)((const char*)ha + row * 512 + ((k0 * 64 + hi * 16) ^ ((row & 7) << 4)));
      }
#pragma unroll
      for (int nt = 0; nt < 4; ++nt) {
        int dc = dblk * 8 + wc * 4 + nt;
        b[nt] = *(const bf16x8*)(wyt + ((size_t)(dc * 8 + k0) * 64 + lane) * 8);
#pragma unroll
        for (int mti = 0; mti < 2; ++mti)
          acc[mti][nt] = __builtin_amdgcn_mfma_f32_16x16x32_bf16(a[mti], b[nt], acc[mti][nt], 0, 0, 0);
      }
    }
#pragma unroll
    for (int mti = 0; mti < 2; ++mti)
#pragma unroll
      for (int nt = 0; nt < 4; ++nt) {
        int d = (dblk * 8 + wc * 4 + nt) * 16 + lr;
        float bv = by[d];
#pragma unroll
        for (int r = 0; r < 4; ++r) {
          int trow = t0 + wr * 32 + mti * 16 + hi * 4 + r;
          y[((size_t)bb * TT + trow) * DD + d] = acc[mti][nt][r] + bv;
        }
      }
  }
}

// ---------------- launch ----------------
extern "C" void kernel_launch(void* const* d_in, const int* in_sizes, int n_in,
                              void* d_out, int out_size, void* d_ws, size_t ws_size,
                              hipStream_t stream) {
  const float* x   = (const float*)d_in[0];
  const float* wih = (const float*)d_in[1];
  const float* bih = (const float*)d_in[2];
  const float* whh = (const float*)d_in[3];
  const float* h0  = (const float*)d_in[4];
  const float* c0  = (const float*)d_in[5];
  const float* wy  = (const float*)d_in[6];
  const float* by  = (const float*)d_in[7];
  float* out = (float*)d_out;
  char* ws = (char*)d_ws;

  size_t off = 0;
  unsigned short* xw = (unsigned short*)(ws + off);
  off += (size_t)(TT + 2) * BG * 2;   // 512MB + 2-row prefetch slack
  unsigned short* wbf = (unsigned short*)(ws + off); off += (size_t)G4 * DD * 2;
  unsigned short* wyt = (unsigned short*)(ws + off); off += (size_t)HH * DD * 2;
  signed char* wq = (signed char*)(ws + off); off += (size_t)G4 * HH;
  float* dsc = (float*)(ws + off); off += G4 * 4;
  float* hh0 = (float*)(ws + off); off += G4 * 4;

  hipLaunchKernelGGL(prep_wih, dim3(1024), dim3(64), 0, stream, wih, wbf);
  hipLaunchKernelGGL(prep_wyt, dim3(256), dim3(256), 0, stream, wy, wyt);
  hipLaunchKernelGGL(prep_whh, dim3(1024), dim3(64), 0, stream, whh, h0, wq, dsc, hh0);
  hipLaunchKernelGGL(xw_gemm, dim3(2048), dim3(256), 0, stream, x, wbf, bih, hh0, xw);
  hipLaunchKernelGGL(lstm_scan, dim3(64), dim3(1024), 0, stream, xw, wq, dsc, c0, out);
  hipLaunchKernelGGL(y_gemm, dim3(4096), dim3(256), 0, stream, xw, wyt, by, out);
}

// Round 17
// 1071.166 us; speedup vs baseline: 1.2963x; 1.0362x over previous
//
#include <hip/hip_runtime.h>
#include <hip/hip_bf16.h>
#include <stdint.h>

#define TT 1024
#define BBATCH 256
#define DD 256
#define HH 256
#define G4 1024   // 4*H
#define BG (BBATCH * G4)

typedef float f32x4 __attribute__((ext_vector_type(4)));
typedef short bf16x8 __attribute__((ext_vector_type(8)));
typedef int   i32x4  __attribute__((ext_vector_type(4)));
typedef unsigned long long u64;

__device__ __forceinline__ float bf2f(unsigned int u) {
  union { unsigned int i; float f; } v; v.i = u << 16; return v.f;
}
__device__ __forceinline__ unsigned short f2bf(float f) {
  union { float f; unsigned int i; } v; v.f = f;
  unsigned int r = v.i + 0x7FFFu + ((v.i >> 16) & 1u);
  return (unsigned short)(r >> 16);
}

// ---------------- merged prep kernel ----------------
// grid 1536 x 256 thr:
//   bid [0,1024):    W_ih -> frag-packed bf16 (1 elem/thread)
//   bid [1024,1280): W_y  -> frag-packed bf16 wyt
//   bid [1280,1536): W_hh -> int8 frags + dsc + hh0 (4 g per block, per-wave reduce)
__global__ void prep_all(const float* __restrict__ wih, const float* __restrict__ wy,
                         const float* __restrict__ whh, const float* __restrict__ h0,
                         unsigned short* __restrict__ wb, unsigned short* __restrict__ wyt,
                         signed char* __restrict__ wq, float* __restrict__ dsc,
                         float* __restrict__ hh0) {
  int bid = blockIdx.x;
  int tid = threadIdx.x;
  if (bid < 1024) {
    int g = bid;
    int sec = g >> 8, n = g & 255;
    int nt8 = n >> 5, wc = (n >> 4) & 1, lr = n & 15;
    int k = tid;
    int ks = k >> 6, kk = (k >> 5) & 1, hi = (k >> 3) & 3, j = k & 7;
    size_t us = (size_t)(nt8 * 4 + ks) * 8192
              + (size_t)((((wc * 4 + sec) * 2 + kk) * 64) + (lr | (hi << 4))) * 8 + j;
    wb[us] = f2bf(wih[g * 256 + k]);
  } else if (bid < 1280) {
    int k = bid - 1024;   // 0..255
    int d = tid;
    int dc = d >> 4, lr = d & 15;
    int k0 = k >> 5, hi = (k >> 3) & 3, el = k & 7;
    wyt[((size_t)(dc * 8 + k0) * 64 + (lr | (hi << 4))) * 8 + el] = f2bf(wy[k * 256 + d]);
  } else {
    int g = (bid - 1280) * 4 + (tid >> 6);
    int lane = tid & 63;
    float v[4];
    float mx = 0.f, acc = 0.f;
#pragma unroll
    for (int j = 0; j < 4; ++j) {
      v[j] = whh[g * 256 + lane * 4 + j];
      mx = fmaxf(mx, fabsf(v[j]));
      acc += v[j] * h0[lane * 4 + j];
    }
#pragma unroll
    for (int off = 32; off; off >>= 1) {
      mx  = fmaxf(mx, __shfl_xor(mx, off));
      acc = acc + __shfl_xor(acc, off);
    }
    mx = fmaxf(mx, 1e-12f);
    if (lane == 0) { dsc[g] = mx / (127.f * 127.f); hh0[g] = acc; }
    int sec = g >> 8, w = (g >> 4) & 15, cl = g & 15;
    float inv = 127.f / mx;
    int k0 = lane * 4;
    int kt = k0 >> 6, hi = (k0 >> 4) & 3, jj = k0 & 15;
    int base = (((w * 4 + sec) * 4 + kt) * 64 + (cl | (hi << 4))) * 16 + jj;
#pragma unroll
    for (int j = 0; j < 4; ++j) {
      int q = (int)rintf(v[j] * inv);
      q = q > 127 ? 127 : (q < -127 ? -127 : q);
      wq[base + j] = (signed char)q;
    }
  }
}

// ---------------- phase 1: xw = x @ W_ih^T + b_ih (gate-packed bf16) ----
// grid 2048, block 256 (4 waves), 2 blocks/CU. One block = 128 trows x ALL 1024 g.
// nt loads on x (read-once), nt stores on xw (write-once -> no RFO).
__global__ __launch_bounds__(256, 2) void xw_gemm(const float* __restrict__ x,
                                                  const unsigned short* __restrict__ wb,
                                                  const float* __restrict__ bih,
                                                  const float* __restrict__ hh0,
                                                  unsigned short* __restrict__ xw) {
  __shared__ __align__(16) char lds[65536];   // A: 128 rows x 512B, XOR-swizzled
  int tid = threadIdx.x;
  int mt = blockIdx.x;          // 0..2047
  int bb = mt >> 3;
  int t0 = (mt & 7) * 128;
  int lane = tid & 63, wv = tid >> 6;
  int wr = wv >> 1, wc = wv & 1;
  int lr = lane & 15, hi = lane >> 4;

  const float* xbase = x + ((size_t)bb * TT + t0) * DD;

  // stage full A-tile: 128 rows x 256 fp32 = 8192 float4 -> 64KB bf16
#pragma unroll 8
  for (int i = 0; i < 32; ++i) {
    int idx = i * 256 + tid;            // float4 index over the tile, 0..8191
    int row = idx >> 6, c4 = idx & 63;
    f32x4 v = __builtin_nontemporal_load((const f32x4*)(xbase + (size_t)idx * 4));
    u64 pk = (u64)f2bf(v[0]) | ((u64)f2bf(v[1]) << 16)
           | ((u64)f2bf(v[2]) << 32) | ((u64)f2bf(v[3]) << 48);
    *(u64*)(lds + row * 512 + ((c4 * 8) ^ ((row & 7) << 4))) = pk;
  }
  __syncthreads();

#pragma unroll 1
  for (int nt8 = 0; nt8 < 8; ++nt8) {
    const unsigned short* wbase = wb + (size_t)nt8 * 4 * 8192;
    f32x4 acc[4][4];   // [mti][sec]
#pragma unroll
    for (int m = 0; m < 4; ++m)
#pragma unroll
      for (int s = 0; s < 4; ++s) acc[m][s] = (f32x4){0.f, 0.f, 0.f, 0.f};
#pragma unroll
    for (int ks = 0; ks < 4; ++ks) {
#pragma unroll
      for (int kk = 0; kk < 2; ++kk) {
        bf16x8 a[4], b[4];
#pragma unroll
        for (int m = 0; m < 4; ++m) {
          int row = wr * 64 + m * 16 + lr;
          a[m] = *(const bf16x8*)(lds + row * 512
                                  + (((ks * 2 + kk) * 64 + hi * 16) ^ ((row & 7) << 4)));
        }
#pragma unroll
        for (int s = 0; s < 4; ++s)
          b[s] = *(const bf16x8*)(wbase + (size_t)ks * 8192
                                  + (size_t)(((wc * 4 + s) * 2 + kk) * 64 + lane) * 8);
#pragma unroll
        for (int m = 0; m < 4; ++m)
#pragma unroll
          for (int s = 0; s < 4; ++s)
            acc[m][s] = __builtin_amdgcn_mfma_f32_16x16x32_bf16(a[m], b[s], acc[m][s], 0, 0, 0);
      }
    }
    // epilogue: pack 4 secs -> u64, add bias (+hh0 at t==0), nt 8B stores
    int n = nt8 * 32 + wc * 16 + lr;
    float bias[4], h0a[4];
#pragma unroll
    for (int s = 0; s < 4; ++s) { bias[s] = bih[s * 256 + n]; h0a[s] = hh0[s * 256 + n]; }
#pragma unroll
    for (int m = 0; m < 4; ++m) {
#pragma unroll
      for (int r = 0; r < 4; ++r) {
        int trow = t0 + wr * 64 + m * 16 + hi * 4 + r;
        float e[4];
#pragma unroll
        for (int s = 0; s < 4; ++s)
          e[s] = acc[m][s][r] + bias[s] + (trow == 0 ? h0a[s] : 0.f);
        u64 pk = (u64)f2bf(e[0]) | ((u64)f2bf(e[1]) << 16)
               | ((u64)f2bf(e[2]) << 32) | ((u64)f2bf(e[3]) << 48);
        __builtin_nontemporal_store(pk, (u64*)(xw + ((size_t)trow * BBATCH + bb) * G4 + (size_t)n * 4));
      }
    }
  }
}

// ---------------- phase 2: the scan ----------------
// 64 blocks x 1024 threads (16 waves, 4/SIMD). hs(t) written lane-contiguous (one full
// 128B line per wave) into the block's OWN batch slice of row t: elem = t*BG + b0*G4 + tid.
// nt loads on xw (read-once), nt stores on hs (no RFO).
__global__ __launch_bounds__(1024, 1) void lstm_scan(unsigned short* xw,
                                                     const signed char* __restrict__ wq,
                                                     const float* __restrict__ dsc,
                                                     const float* __restrict__ c0,
                                                     float* __restrict__ out) {
  __shared__ __align__(16) signed char hq[2][4][64][16];  // 8KB, double-buffered int8 h A-frags
  int tid = threadIdx.x;
  int lane = tid & 63, wv = tid >> 6;
  int lr = lane & 15, q = lane >> 4;
  int b0 = blockIdx.x * 4;
  signed char* hqb = (signed char*)hq;
  int nn = wv * 16 + lr;

  // resident W_hh int8 B-frags: 16 i32x4 = 64 VGPRs
  i32x4 wf[4][4];
  {
    const i32x4* wp = (const i32x4*)wq;
#pragma unroll
    for (int sec = 0; sec < 4; ++sec)
#pragma unroll
      for (int kt = 0; kt < 4; ++kt) wf[sec][kt] = wp[((wv * 4 + sec) * 4 + kt) * 64 + lane];
  }
  float dr[4];
#pragma unroll
  for (int sec = 0; sec < 4; ++sec) dr[sec] = dsc[sec * 256 + nn];
  float cr = c0[nn], lh = 0.f;

  // zero both hq buffers (8KB = 1024 threads * 8B)
  *(u64*)(hqb + tid * 8) = 0ull;

  // per-lane pointers
  unsigned short* ldb = xw + (size_t)(b0 + q) * G4 + (size_t)nn * 4;
  unsigned short* hsp = xw + (size_t)b0 * G4 + tid;   // hs store base (block-own slice, row += t)
  u64 xq[4];
#pragma unroll
  for (int s = 0; s < 2; ++s) {
    xq[s] = __builtin_nontemporal_load((const u64*)ldb);
    ldb += (size_t)BG;
  }

  const int hqr = lane * 16;
  // producer write: kt = wv>>2, hi = wv&3, row = 4q, byte j = lr
  const int hqw = (wv >> 2) * 1024 + (wv & 3) * 256 + q * 64 + lr;
  const i32x4 zero4 = {0, 0, 0, 0};

  __syncthreads();  // hq zero visible

#define STEP(XC, XL, RB) { \
    XL = __builtin_nontemporal_load((const u64*)ldb); \
    ldb += (size_t)BG; \
    i32x4 acc[4]; \
    __builtin_amdgcn_s_setprio(1); \
    _Pragma("unroll") \
    for (int kt = 0; kt < 4; ++kt) { \
      i32x4 af = *(const i32x4*)(hqb + (RB) + hqr + kt * 1024); \
      _Pragma("unroll") \
      for (int sec = 0; sec < 4; ++sec) \
        acc[sec] = __builtin_amdgcn_mfma_i32_16x16x64_i8(af, wf[sec][kt], kt == 0 ? zero4 : acc[sec], 0, 0, 0); \
    } \
    __builtin_amdgcn_s_setprio(0); \
    { \
      u64 v = XC; \
      float gi = fmaf(dr[0], (float)acc[0][0], bf2f((unsigned int)(v & 0xffffu))); \
      float gf = fmaf(dr[1], (float)acc[1][0], bf2f((unsigned int)((v >> 16) & 0xffffu))); \
      float gj = fmaf(dr[2], (float)acc[2][0], bf2f((unsigned int)((v >> 32) & 0xffffu))); \
      float go = fmaf(dr[3], (float)acc[3][0], bf2f((unsigned int)(v >> 48))); \
      float iv = __builtin_amdgcn_rcpf(1.f + __expf(-gi)); \
      float fv = __builtin_amdgcn_rcpf(1.f + __expf(-gf)); \
      float ov = __builtin_amdgcn_rcpf(1.f + __expf(-go)); \
      float jv = fmaf(-2.f, __builtin_amdgcn_rcpf(1.f + __expf(2.f * gj)), 1.f); \
      float cn = fmaf(fv, cr, iv * jv); \
      cr = cn; \
      float th = fmaf(-2.f, __builtin_amdgcn_rcpf(1.f + __expf(2.f * cn)), 1.f); \
      float hn = ov * th; \
      lh = hn; \
      hqb[((RB) ^ 4096) + hqw] = (signed char)(int)rintf(hn * 127.f); \
      __builtin_nontemporal_store((unsigned short)f2bf(hn), hsp); \
    } \
    hsp += (size_t)BG; \
    asm volatile("s_waitcnt lgkmcnt(0)" ::: "memory"); \
    __builtin_amdgcn_s_barrier(); \
  }

#pragma unroll 1
  for (int t = 0; t < TT; t += 4) {
    STEP(xq[0], xq[2], 0)
    STEP(xq[1], xq[3], 4096)
    STEP(xq[2], xq[0], 0)
    STEP(xq[3], xq[1], 4096)
  }
#undef STEP

  const size_t youts = (size_t)BBATCH * TT * DD;
  out[youts + (size_t)(b0 + q) * HH + nn] = lh;
  out[youts + (size_t)BBATCH * HH + (size_t)(b0 + q) * HH + nn] = cr;
}

// ---------------- phase 3: y = hs @ W_y + b_y ----------------
// hs element (t,b,n) at elem t*BG + (b>>2)*4096 + (n>>4)*64 + (b&3)*16 + (n&15).
// wyt frag-packed; nt loads on hs, nt stores on y.
__global__ __launch_bounds__(256, 4) void y_gemm(const unsigned short* __restrict__ hsx,
                                                 const unsigned short* __restrict__ wyt,
                                                 const float* __restrict__ by,
                                                 float* __restrict__ y) {
  __shared__ __align__(16) unsigned short ha[64 * 256];  // 32KB
  int tid = threadIdx.x;
  int mt = blockIdx.x;
  int bb = mt >> 4;
  int t0 = (mt & 15) * 64;
  {
    int row = tid >> 2, qt = tid & 3;
    int t = t0 + row;
    const unsigned short* src = hsx + (size_t)t * BG + (size_t)(bb >> 2) * 4096 + (bb & 3) * 16;
#pragma unroll
    for (int i = 0; i < 8; ++i) {
      int u = qt + i * 4;   // 16B unit, 0..31
      i32x4 vv = __builtin_nontemporal_load((const i32x4*)(src + (u >> 1) * 64 + (u & 1) * 8));
      *(i32x4*)((char*)ha + row * 512 + ((u * 16) ^ ((row & 7) << 4))) = vv;
    }
  }
  __syncthreads();
  int lane = tid & 63, wv = tid >> 6;
  int wr = wv >> 1, wc = wv & 1;
  int lr = lane & 15, hi = lane >> 4;
#pragma unroll 1
  for (int dblk = 0; dblk < 2; ++dblk) {
    f32x4 acc[2][4];
#pragma unroll
    for (int a = 0; a < 2; ++a)
#pragma unroll
      for (int b = 0; b < 4; ++b) acc[a][b] = (f32x4){0.f, 0.f, 0.f, 0.f};
#pragma unroll
    for (int k0 = 0; k0 < 8; ++k0) {
      bf16x8 a[2], b[4];
#pragma unroll
      for (int mti = 0; mti < 2; ++mti) {
        int row = wr * 32 + mti * 16 + lr;
        a[mti] = *(const bf16x8*)((const char*)ha + row * 512 + ((k0 * 64 + hi * 16) ^ ((row & 7) << 4)));
      }
#pragma unroll
      for (int nt = 0; nt < 4; ++nt) {
        int dc = dblk * 8 + wc * 4 + nt;
        b[nt] = *(const bf16x8*)(wyt + ((size_t)(dc * 8 + k0) * 64 + lane) * 8);
#pragma unroll
        for (int mti = 0; mti < 2; ++mti)
          acc[mti][nt] = __builtin_amdgcn_mfma_f32_16x16x32_bf16(a[mti], b[nt], acc[mti][nt], 0, 0, 0);
      }
    }
#pragma unroll
    for (int mti = 0; mti < 2; ++mti)
#pragma unroll
      for (int nt = 0; nt < 4; ++nt) {
        int d = (dblk * 8 + wc * 4 + nt) * 16 + lr;
        float bv = by[d];
#pragma unroll
        for (int r = 0; r < 4; ++r) {
          int trow = t0 + wr * 32 + mti * 16 + hi * 4 + r;
          __builtin_nontemporal_store(acc[mti][nt][r] + bv,
                                      y + ((size_t)bb * TT + trow) * DD + d);
        }
      }
  }
}

// ---------------- launch ----------------
extern "C" void kernel_launch(void* const* d_in, const int* in_sizes, int n_in,
                              void* d_out, int out_size, void* d_ws, size_t ws_size,
                              hipStream_t stream) {
  const float* x   = (const float*)d_in[0];
  const float* wih = (const float*)d_in[1];
  const float* bih = (const float*)d_in[2];
  const float* whh = (const float*)d_in[3];
  const float* h0  = (const float*)d_in[4];
  const float* c0  = (const float*)d_in[5];
  const float* wy  = (const float*)d_in[6];
  const float* by  = (const float*)d_in[7];
  float* out = (float*)d_out;
  char* ws = (char*)d_ws;

  size_t off = 0;
  unsigned short* xw = (unsigned short*)(ws + off);
  off += (size_t)(TT + 2) * BG * 2;   // 512MB + 2-row prefetch slack
  unsigned short* wbf = (unsigned short*)(ws + off); off += (size_t)G4 * DD * 2;
  unsigned short* wyt = (unsigned short*)(ws + off); off += (size_t)HH * DD * 2;
  signed char* wq = (signed char*)(ws + off); off += (size_t)G4 * HH;
  float* dsc = (float*)(ws + off); off += G4 * 4;
  float* hh0 = (float*)(ws + off); off += G4 * 4;

  hipLaunchKernelGGL(prep_all, dim3(1536), dim3(256), 0, stream,
                     wih, wy, whh, h0, wbf, wyt, wq, dsc, hh0);
  hipLaunchKernelGGL(xw_gemm, dim3(2048), dim3(256), 0, stream, x, wbf, bih, hh0, xw);
  hipLaunchKernelGGL(lstm_scan, dim3(64), dim3(1024), 0, stream, xw, wq, dsc, c0, out);
  hipLaunchKernelGGL(y_gemm, dim3(4096), dim3(256), 0, stream, xw, wyt, by, out);
}